// Round 4
// baseline (78.824 us; speedup 1.0000x reference)
//
#include <hip/hip_runtime.h>

// GCNEncoder on fully-connected graph: GCNConv == broadcast of per-graph mean.
//   out0 = log_softmax( relu( (mean_i(x) @ W0 + b0) @ W1 + b1 ) @ W2 + b2 )  broadcast over nodes
//   out1 = x @ W0 + b0   (node_feature)
// DTYPE EVIDENCE (rounds 0-3): inputs fp32 (R1 bf16-misread => NaN), output
// fp32 (R3 bf16 writes re-read as fp32 => the exact 7.92 permutation
// signature). R2's abort was an infra flake: R3 performed identical reads
// without faulting and all writes are provably in-bounds for 4 MiB fp32.
// edge_index (d_in[7]) eliminated analytically: deg == N for every node =>
// norm == 1/N and scatter-add == mean over nodes, which commutes with matmul.

#define B_ 8
#define N_ 512
#define D_ 128

__global__ __launch_bounds__(256) void gcn_fused_kernel(
    const float* __restrict__ x,    // [B,N,2]
    const float* __restrict__ W0,   // [2,D]
    const float* __restrict__ b0,   // [D]
    const float* __restrict__ W1,   // [D,D]
    const float* __restrict__ b1,   // [D]
    const float* __restrict__ W2,   // [D,D]
    const float* __restrict__ b2,   // [D]
    float* __restrict__ out)        // [2,B,N,D] flat fp32: out0 then out1
{
    __shared__ float s_mnf[D_];
    __shared__ float s_h1[D_];
    __shared__ float s_ls[D_];
    __shared__ float s_red[8];

    const int tid = threadIdx.x;
    const int blk = blockIdx.x;
    const int b   = blk >> 5;          // 32 blocks per batch
    const int n0  = (blk & 31) << 4;   // 16 nodes per block

    // ---- Step 1: mean of x over the 512 nodes of batch b (2 coords) ----
    // batch slab: 512*2 = 1024 floats; 256 threads * float4 = 1024 exactly.
    const float4* xb4 = (const float4*)(x + (size_t)b * N_ * 2);
    float4 v = xb4[tid];
    float s0 = v.x + v.z;  // even flat idx -> coord 0
    float s1 = v.y + v.w;  // odd  flat idx -> coord 1
    #pragma unroll
    for (int m = 1; m < 64; m <<= 1) {
        s0 += __shfl_xor(s0, m);
        s1 += __shfl_xor(s1, m);
    }
    const int wave = tid >> 6;
    if ((tid & 63) == 0) { s_red[wave] = s0; s_red[4 + wave] = s1; }
    __syncthreads();
    const float mx0 = (s_red[0] + s_red[1] + s_red[2] + s_red[3]) * (1.0f / N_);
    const float mx1 = (s_red[4] + s_red[5] + s_red[6] + s_red[7]) * (1.0f / N_);
    __syncthreads();  // protect s_red before reuse in softmax reductions

    // ---- Step 2: mean node feature = mx @ W0 + b0 ----
    if (tid < D_) {
        s_mnf[tid] = fmaf(mx0, W0[tid], fmaf(mx1, W0[D_ + tid], b0[tid]));
    }
    __syncthreads();

    // ---- Step 3: h1 = relu(mnf @ W1 + b1) ----
    if (tid < D_) {
        float g = b1[tid];
        #pragma unroll 8
        for (int k = 0; k < D_; ++k)
            g = fmaf(s_mnf[k], W1[k * D_ + tid], g);
        s_h1[tid] = fmaxf(g, 0.0f);
    }
    __syncthreads();

    // ---- Step 4: g2 = h1 @ W2 + b2 ----
    float g2 = -1e30f;
    if (tid < D_) {
        float g = b2[tid];
        #pragma unroll 8
        for (int k = 0; k < D_; ++k)
            g = fmaf(s_h1[k], W2[k * D_ + tid], g);
        g2 = g;
    }

    // ---- Step 5: log_softmax over the 128 values held by tid 0..127 ----
    float m = g2;
    #pragma unroll
    for (int msk = 1; msk < 64; msk <<= 1) m = fmaxf(m, __shfl_xor(m, msk));
    if ((tid & 63) == 0) s_red[wave] = m;
    __syncthreads();
    const float gmax = fmaxf(s_red[0], s_red[1]);
    float e = (tid < D_) ? __expf(g2 - gmax) : 0.0f;
    float se = e;
    #pragma unroll
    for (int msk = 1; msk < 64; msk <<= 1) se += __shfl_xor(se, msk);
    if ((tid & 63) == 0) s_red[4 + wave] = se;
    __syncthreads();
    const float lse = __logf(s_red[4] + s_red[5]) + gmax;
    if (tid < D_) s_ls[tid] = g2 - lse;
    __syncthreads();

    // ---- Step 6: write outputs for this block's 16 nodes ----
    // thread -> (node, d-chunk of 8); two float4 stores per output tensor.
    const int node  = n0 + (tid >> 4);
    const int d0    = (tid & 15) << 3;
    const int gnode = b * N_ + node;
    const float x0 = x[gnode * 2 + 0];
    const float x1 = x[gnode * 2 + 1];

    float o1[8];  // log_softmax (broadcast per batch)
    float o2[8];  // node_feature
    #pragma unroll
    for (int j = 0; j < 8; ++j) {
        const int d = d0 + j;
        o1[j] = s_ls[d];
        o2[j] = fmaf(x0, W0[d], fmaf(x1, W0[D_ + d], b0[d]));
    }
    const size_t off  = (size_t)gnode * D_ + d0;
    const size_t off2 = (size_t)B_ * N_ * D_ + off;
    *(float4*)(out + off)      = make_float4(o1[0], o1[1], o1[2], o1[3]);
    *(float4*)(out + off + 4)  = make_float4(o1[4], o1[5], o1[6], o1[7]);
    *(float4*)(out + off2)     = make_float4(o2[0], o2[1], o2[2], o2[3]);
    *(float4*)(out + off2 + 4) = make_float4(o2[4], o2[5], o2[6], o2[7]);
}

extern "C" void kernel_launch(void* const* d_in, const int* in_sizes, int n_in,
                              void* d_out, int out_size, void* d_ws, size_t ws_size,
                              hipStream_t stream) {
    const float* x  = (const float*)d_in[0];
    const float* W0 = (const float*)d_in[1];
    const float* b0 = (const float*)d_in[2];
    const float* W1 = (const float*)d_in[3];
    const float* b1 = (const float*)d_in[4];
    const float* W2 = (const float*)d_in[5];
    const float* b2 = (const float*)d_in[6];
    // d_in[7] = edge_index (int32) — eliminated analytically.
    float* out = (float*)d_out;

    dim3 grid(256), block(256);
    hipLaunchKernelGGL(gcn_fused_kernel, grid, block, 0, stream,
                       x, W0, b0, W1, b1, W2, b2, out);
}

// Round 5
// 72.698 us; speedup vs baseline: 1.0843x; 1.0843x over previous
//
#include <hip/hip_runtime.h>

// GCNEncoder on fully-connected graph: GCNConv == broadcast of per-graph mean.
//   out0 = log_softmax( relu( (mean_i(x) @ W0 + b0) @ W1 + b1 ) @ W2 + b2 )  broadcast
//   out1 = x @ W0 + b0   (node_feature)
// fp32 in / fp32 out (validated R4: absmax 6.1e-5, passed).
// R5 change: split-K matvec — both 128-thread halves of the block each do a
// 64-deep K-chain (was one half idle doing a 128-deep chain), partials
// combined in LDS. Halves the load-latency-bound dependent chain.

#define B_ 8
#define N_ 512
#define D_ 128

__global__ __launch_bounds__(256) void gcn_fused_kernel(
    const float* __restrict__ x,    // [B,N,2]
    const float* __restrict__ W0,   // [2,D]
    const float* __restrict__ b0,   // [D]
    const float* __restrict__ W1,   // [D,D]
    const float* __restrict__ b1,   // [D]
    const float* __restrict__ W2,   // [D,D]
    const float* __restrict__ b2,   // [D]
    float* __restrict__ out)        // [2,B,N,D] flat fp32: out0 then out1
{
    __shared__ float s_mnf[D_];
    __shared__ float s_h1[D_];
    __shared__ float s_ls[D_];
    __shared__ float s_part[256];
    __shared__ float s_red[8];

    const int tid = threadIdx.x;
    const int blk = blockIdx.x;
    const int b   = blk >> 5;          // 32 blocks per batch
    const int n0  = (blk & 31) << 4;   // 16 nodes per block
    const int d    = tid & 127;        // output column for split-K matvec
    const int half = tid >> 7;         // K-half (0: k<64, 1: k>=64)

    // ---- Step 1: mean of x over the 512 nodes of batch b (2 coords) ----
    const float4* xb4 = (const float4*)(x + (size_t)b * N_ * 2);
    float4 v = xb4[tid];
    float s0 = v.x + v.z;  // even flat idx -> coord 0
    float s1 = v.y + v.w;  // odd  flat idx -> coord 1
    #pragma unroll
    for (int m = 1; m < 64; m <<= 1) {
        s0 += __shfl_xor(s0, m);
        s1 += __shfl_xor(s1, m);
    }
    const int wave = tid >> 6;
    if ((tid & 63) == 0) { s_red[wave] = s0; s_red[4 + wave] = s1; }
    __syncthreads();
    const float mx0 = (s_red[0] + s_red[1] + s_red[2] + s_red[3]) * (1.0f / N_);
    const float mx1 = (s_red[4] + s_red[5] + s_red[6] + s_red[7]) * (1.0f / N_);
    __syncthreads();  // protect s_red before reuse in softmax reductions

    // ---- Step 2: mean node feature = mx @ W0 + b0 ----
    if (tid < D_) {
        s_mnf[tid] = fmaf(mx0, W0[tid], fmaf(mx1, W0[D_ + tid], b0[tid]));
    }
    __syncthreads();

    // ---- Step 3: h1 = relu(mnf @ W1 + b1), split-K across the two halves ----
    {
        float g = half ? 0.0f : b1[d];
        const float* __restrict__ W1h  = W1 + (size_t)half * 64 * D_ + d;
        const float* __restrict__ mnfh = s_mnf + half * 64;
        #pragma unroll 16
        for (int k = 0; k < 64; ++k)
            g = fmaf(mnfh[k], W1h[(size_t)k * D_], g);
        s_part[tid] = g;
    }
    __syncthreads();
    if (tid < D_) s_h1[tid] = fmaxf(s_part[tid] + s_part[tid + 128], 0.0f);
    __syncthreads();

    // ---- Step 4: g2 = h1 @ W2 + b2, split-K ----
    {
        float g = half ? 0.0f : b2[d];
        const float* __restrict__ W2h = W2 + (size_t)half * 64 * D_ + d;
        const float* __restrict__ h1h = s_h1 + half * 64;
        #pragma unroll 16
        for (int k = 0; k < 64; ++k)
            g = fmaf(h1h[k], W2h[(size_t)k * D_], g);
        s_part[tid] = g;
    }
    __syncthreads();
    float g2 = -1e30f;
    if (tid < D_) g2 = s_part[tid] + s_part[tid + 128];

    // ---- Step 5: log_softmax over the 128 values held by tid 0..127 ----
    float m = g2;
    #pragma unroll
    for (int msk = 1; msk < 64; msk <<= 1) m = fmaxf(m, __shfl_xor(m, msk));
    if ((tid & 63) == 0) s_red[wave] = m;
    __syncthreads();
    const float gmax = fmaxf(s_red[0], s_red[1]);
    float e = (tid < D_) ? __expf(g2 - gmax) : 0.0f;
    float se = e;
    #pragma unroll
    for (int msk = 1; msk < 64; msk <<= 1) se += __shfl_xor(se, msk);
    if ((tid & 63) == 0) s_red[4 + wave] = se;
    __syncthreads();
    const float lse = __logf(s_red[4] + s_red[5]) + gmax;
    if (tid < D_) s_ls[tid] = g2 - lse;
    __syncthreads();

    // ---- Step 6: write outputs for this block's 16 nodes ----
    const int node  = n0 + (tid >> 4);
    const int d0    = (tid & 15) << 3;
    const int gnode = b * N_ + node;
    const float x0 = x[gnode * 2 + 0];
    const float x1 = x[gnode * 2 + 1];

    float o1[8];  // log_softmax (broadcast per batch)
    float o2[8];  // node_feature
    #pragma unroll
    for (int j = 0; j < 8; ++j) {
        const int dd = d0 + j;
        o1[j] = s_ls[dd];
        o2[j] = fmaf(x0, W0[dd], fmaf(x1, W0[D_ + dd], b0[dd]));
    }
    const size_t off  = (size_t)gnode * D_ + d0;
    const size_t off2 = (size_t)B_ * N_ * D_ + off;
    *(float4*)(out + off)      = make_float4(o1[0], o1[1], o1[2], o1[3]);
    *(float4*)(out + off + 4)  = make_float4(o1[4], o1[5], o1[6], o1[7]);
    *(float4*)(out + off2)     = make_float4(o2[0], o2[1], o2[2], o2[3]);
    *(float4*)(out + off2 + 4) = make_float4(o2[4], o2[5], o2[6], o2[7]);
}

extern "C" void kernel_launch(void* const* d_in, const int* in_sizes, int n_in,
                              void* d_out, int out_size, void* d_ws, size_t ws_size,
                              hipStream_t stream) {
    const float* x  = (const float*)d_in[0];
    const float* W0 = (const float*)d_in[1];
    const float* b0 = (const float*)d_in[2];
    const float* W1 = (const float*)d_in[3];
    const float* b1 = (const float*)d_in[4];
    const float* W2 = (const float*)d_in[5];
    const float* b2 = (const float*)d_in[6];
    // d_in[7] = edge_index (int32) — eliminated analytically.
    float* out = (float*)d_out;

    dim3 grid(256), block(256);
    hipLaunchKernelGGL(gcn_fused_kernel, grid, block, 0, stream,
                       x, W0, b0, W1, b1, W2, b2, out);
}

// Round 6
// 71.482 us; speedup vs baseline: 1.1027x; 1.0170x over previous
//
#include <hip/hip_runtime.h>

// GCNEncoder on fully-connected graph: GCNConv == broadcast of per-graph mean.
//   out0 = log_softmax( relu( (mean_i(x) @ W0 + b0) @ W1 + b1 ) @ W2 + b2 )  broadcast
//   out1 = x @ W0 + b0   (node_feature)
// fp32 in / fp32 out (validated R4/R5). edge_index eliminated analytically.
// R6: 512-thread block + split-K=4 (32-deep chains, was 64) + out1 stored
// EARLY (before the W1/W2 chain) so its 2 MiB of stores overlap the
// latency-bound matvec chain. Every replay runs cold (ws-poison flushes L2),
// so the chain is HBM-latency dominated; fewer sequential latency groups.

#define B_ 8
#define N_ 512
#define D_ 128

__global__ __launch_bounds__(512) void gcn_fused_kernel(
    const float* __restrict__ x,    // [B,N,2]
    const float* __restrict__ W0,   // [2,D]
    const float* __restrict__ b0,   // [D]
    const float* __restrict__ W1,   // [D,D]
    const float* __restrict__ b1,   // [D]
    const float* __restrict__ W2,   // [D,D]
    const float* __restrict__ b2,   // [D]
    float* __restrict__ out)        // [2,B,N,D] flat fp32: out0 then out1
{
    __shared__ float s_mnf[D_];
    __shared__ float s_h1[D_];
    __shared__ float s_ls[D_];
    __shared__ float s_part[512];
    __shared__ float s_red[16];

    const int tid = threadIdx.x;
    const int blk = blockIdx.x;
    const int b   = blk >> 5;          // 32 blocks per batch
    const int n0  = (blk & 31) << 4;   // 16 nodes per block
    const int d   = tid & 127;         // output column for split-K matvec
    const int q   = tid >> 7;          // K-quarter (0..3)
    const int wave = tid >> 6;

    // ---- Step 1: mean of x over the 512 nodes of batch b (2 coords) ----
    // batch slab: 512*2 = 1024 floats; 512 threads * float2 = 1024 exactly.
    const float2* xb2 = (const float2*)(x + (size_t)b * N_ * 2);
    float2 v = xb2[tid];               // node tid's (coord0, coord1)
    float s0 = v.x;
    float s1 = v.y;
    #pragma unroll
    for (int m = 1; m < 64; m <<= 1) {
        s0 += __shfl_xor(s0, m);
        s1 += __shfl_xor(s1, m);
    }
    if ((tid & 63) == 0) { s_red[wave] = s0; s_red[8 + wave] = s1; }

    // ---- Step A: compute & store out1 early (only needs x, W0, b0) ----
    // thread -> (node, 4-wide d chunk): 32 threads/node * 4 d = 128.
    const int node  = n0 + (tid >> 5);
    const int d0    = (tid & 31) << 2;
    const int gnode = b * N_ + node;
    const float x0 = x[gnode * 2 + 0];   // L1-hot after step-1 slab load
    const float x1 = x[gnode * 2 + 1];
    {
        float o2[4];
        #pragma unroll
        for (int j = 0; j < 4; ++j) {
            const int dd = d0 + j;
            o2[j] = fmaf(x0, W0[dd], fmaf(x1, W0[D_ + dd], b0[dd]));
        }
        const size_t off2 = (size_t)B_ * N_ * D_ + (size_t)gnode * D_ + d0;
        *(float4*)(out + off2) = make_float4(o2[0], o2[1], o2[2], o2[3]);
    }

    __syncthreads();
    const float mx0 = (s_red[0] + s_red[1] + s_red[2] + s_red[3] +
                       s_red[4] + s_red[5] + s_red[6] + s_red[7]) * (1.0f / N_);
    const float mx1 = (s_red[8] + s_red[9] + s_red[10] + s_red[11] +
                       s_red[12] + s_red[13] + s_red[14] + s_red[15]) * (1.0f / N_);
    __syncthreads();  // protect s_red before reuse in softmax reductions

    // ---- Step 2: mean node feature = mx @ W0 + b0 (W0/b0 now L1-hot) ----
    if (tid < D_) {
        s_mnf[tid] = fmaf(mx0, W0[tid], fmaf(mx1, W0[D_ + tid], b0[tid]));
    }
    __syncthreads();

    // ---- Step 3: h1 = relu(mnf @ W1 + b1), split-K=4 (32-deep chains) ----
    {
        float g = (q == 0) ? b1[d] : 0.0f;
        const float* __restrict__ W1h  = W1 + (size_t)(q * 32) * D_ + d;
        const float* __restrict__ mnfh = s_mnf + q * 32;
        #pragma unroll
        for (int k = 0; k < 32; ++k)
            g = fmaf(mnfh[k], W1h[(size_t)k * D_], g);
        s_part[tid] = g;
    }
    __syncthreads();
    if (tid < D_)
        s_h1[tid] = fmaxf(s_part[tid] + s_part[tid + 128] +
                          s_part[tid + 256] + s_part[tid + 384], 0.0f);
    __syncthreads();

    // ---- Step 4: g2 = h1 @ W2 + b2, split-K=4 ----
    {
        float g = (q == 0) ? b2[d] : 0.0f;
        const float* __restrict__ W2h = W2 + (size_t)(q * 32) * D_ + d;
        const float* __restrict__ h1h = s_h1 + q * 32;
        #pragma unroll
        for (int k = 0; k < 32; ++k)
            g = fmaf(h1h[k], W2h[(size_t)k * D_], g);
        s_part[tid] = g;
    }
    __syncthreads();
    float g2 = -1e30f;
    if (tid < D_)
        g2 = s_part[tid] + s_part[tid + 128] + s_part[tid + 256] + s_part[tid + 384];

    // ---- Step 5: log_softmax over the 128 values held by tid 0..127 ----
    float m = g2;
    #pragma unroll
    for (int msk = 1; msk < 64; msk <<= 1) m = fmaxf(m, __shfl_xor(m, msk));
    if ((tid & 63) == 0) s_red[wave] = m;   // waves 2..7 write unused slots
    __syncthreads();
    const float gmax = fmaxf(s_red[0], s_red[1]);
    float e = (tid < D_) ? __expf(g2 - gmax) : 0.0f;
    float se = e;
    #pragma unroll
    for (int msk = 1; msk < 64; msk <<= 1) se += __shfl_xor(se, msk);
    if ((tid & 63) == 0) s_red[8 + wave] = se;
    __syncthreads();
    const float lse = __logf(s_red[8] + s_red[9]) + gmax;
    if (tid < D_) s_ls[tid] = g2 - lse;
    __syncthreads();

    // ---- Step 6: store out0 (broadcast ls) for this block's 16 nodes ----
    {
        const size_t off = (size_t)gnode * D_ + d0;
        *(float4*)(out + off) =
            make_float4(s_ls[d0], s_ls[d0 + 1], s_ls[d0 + 2], s_ls[d0 + 3]);
    }
}

extern "C" void kernel_launch(void* const* d_in, const int* in_sizes, int n_in,
                              void* d_out, int out_size, void* d_ws, size_t ws_size,
                              hipStream_t stream) {
    const float* x  = (const float*)d_in[0];
    const float* W0 = (const float*)d_in[1];
    const float* b0 = (const float*)d_in[2];
    const float* W1 = (const float*)d_in[3];
    const float* b1 = (const float*)d_in[4];
    const float* W2 = (const float*)d_in[5];
    const float* b2 = (const float*)d_in[6];
    // d_in[7] = edge_index (int32) — eliminated analytically.
    float* out = (float*)d_out;

    dim3 grid(256), block(512);
    hipLaunchKernelGGL(gcn_fused_kernel, grid, block, 0, stream,
                       x, W0, b0, W1, b1, W2, b2, out);
}

// Round 7
// 71.180 us; speedup vs baseline: 1.1074x; 1.0042x over previous
//
#include <hip/hip_runtime.h>

// GCNEncoder on fully-connected graph: GCNConv == broadcast of per-graph mean.
//   out0 = log_softmax( relu( (mean_i(x) @ W0 + b0) @ W1 + b1 ) @ W2 + b2 )  broadcast
//   out1 = x @ W0 + b0   (node_feature)
// fp32 in / fp32 out (validated R4-R6). edge_index eliminated analytically.
// R7: register-prefetch W1 AND W2 slices at kernel entry (addresses are
// static per-thread), so both cold-HBM round-trips (~900 cyc each) overlap
// the mean-reduction + the early 2 MiB out1 store burst instead of
// serializing the matvec chains. Chains become pure register-FMA + LDS.

#define B_ 8
#define N_ 512
#define D_ 128

__global__ __launch_bounds__(512) void gcn_fused_kernel(
    const float* __restrict__ x,    // [B,N,2]
    const float* __restrict__ W0,   // [2,D]
    const float* __restrict__ b0,   // [D]
    const float* __restrict__ W1,   // [D,D]
    const float* __restrict__ b1,   // [D]
    const float* __restrict__ W2,   // [D,D]
    const float* __restrict__ b2,   // [D]
    float* __restrict__ out)        // [2,B,N,D] flat fp32: out0 then out1
{
    __shared__ float s_mnf[D_];
    __shared__ float s_h1[D_];
    __shared__ float s_ls[D_];
    __shared__ float s_part[512];
    __shared__ float s_red[16];

    const int tid = threadIdx.x;
    const int blk = blockIdx.x;
    const int b   = blk >> 5;          // 32 blocks per batch
    const int n0  = (blk & 31) << 4;   // 16 nodes per block
    const int d   = tid & 127;         // output column for split-K matvec
    const int q   = tid >> 7;          // K-quarter (0..3)
    const int wave = tid >> 6;

    // ---- Prefetch: issue ALL weight loads up front (static addresses) ----
    const float* __restrict__ W1h = W1 + (size_t)(q * 32) * D_ + d;
    const float* __restrict__ W2h = W2 + (size_t)(q * 32) * D_ + d;
    float w1r[32], w2r[32];
    #pragma unroll
    for (int k = 0; k < 32; ++k) w1r[k] = W1h[(size_t)k * D_];
    #pragma unroll
    for (int k = 0; k < 32; ++k) w2r[k] = W2h[(size_t)k * D_];
    const float bias1 = (q == 0) ? b1[d] : 0.0f;
    const float bias2 = (q == 0) ? b2[d] : 0.0f;

    // ---- Step 1: mean of x over the 512 nodes of batch b (2 coords) ----
    // batch slab: 512*2 = 1024 floats; 512 threads * float2 = 1024 exactly.
    const float2* xb2 = (const float2*)(x + (size_t)b * N_ * 2);
    float2 v = xb2[tid];               // node tid's (coord0, coord1)
    float s0 = v.x;
    float s1 = v.y;
    #pragma unroll
    for (int m = 1; m < 64; m <<= 1) {
        s0 += __shfl_xor(s0, m);
        s1 += __shfl_xor(s1, m);
    }
    if ((tid & 63) == 0) { s_red[wave] = s0; s_red[8 + wave] = s1; }

    // ---- Step A: compute & store out1 early (only needs x, W0, b0) ----
    // thread -> (node, 4-wide d chunk): 32 threads/node * 4 d = 128.
    const int node  = n0 + (tid >> 5);
    const int d0    = (tid & 31) << 2;
    const int gnode = b * N_ + node;
    const float x0 = x[gnode * 2 + 0];   // L1-hot after step-1 slab load
    const float x1 = x[gnode * 2 + 1];
    {
        float o2[4];
        #pragma unroll
        for (int j = 0; j < 4; ++j) {
            const int dd = d0 + j;
            o2[j] = fmaf(x0, W0[dd], fmaf(x1, W0[D_ + dd], b0[dd]));
        }
        const size_t off2 = (size_t)B_ * N_ * D_ + (size_t)gnode * D_ + d0;
        *(float4*)(out + off2) = make_float4(o2[0], o2[1], o2[2], o2[3]);
    }

    __syncthreads();
    const float mx0 = (s_red[0] + s_red[1] + s_red[2] + s_red[3] +
                       s_red[4] + s_red[5] + s_red[6] + s_red[7]) * (1.0f / N_);
    const float mx1 = (s_red[8] + s_red[9] + s_red[10] + s_red[11] +
                       s_red[12] + s_red[13] + s_red[14] + s_red[15]) * (1.0f / N_);
    __syncthreads();  // protect s_red before reuse in softmax reductions

    // ---- Step 2: mean node feature = mx @ W0 + b0 (W0/b0 L1-hot) ----
    if (tid < D_) {
        s_mnf[tid] = fmaf(mx0, W0[tid], fmaf(mx1, W0[D_ + tid], b0[tid]));
    }
    __syncthreads();

    // ---- Step 3: h1 = relu(mnf @ W1 + b1), split-K=4, weights in regs ----
    {
        float g = bias1;
        const float* __restrict__ mnfh = s_mnf + q * 32;
        #pragma unroll
        for (int k = 0; k < 32; ++k)
            g = fmaf(mnfh[k], w1r[k], g);
        s_part[tid] = g;
    }
    __syncthreads();
    if (tid < D_)
        s_h1[tid] = fmaxf(s_part[tid] + s_part[tid + 128] +
                          s_part[tid + 256] + s_part[tid + 384], 0.0f);
    __syncthreads();

    // ---- Step 4: g2 = h1 @ W2 + b2, split-K=4, weights in regs ----
    {
        float g = bias2;
        const float* __restrict__ h1h = s_h1 + q * 32;
        #pragma unroll
        for (int k = 0; k < 32; ++k)
            g = fmaf(h1h[k], w2r[k], g);
        s_part[tid] = g;
    }
    __syncthreads();
    float g2 = -1e30f;
    if (tid < D_)
        g2 = s_part[tid] + s_part[tid + 128] + s_part[tid + 256] + s_part[tid + 384];

    // ---- Step 5: log_softmax over the 128 values held by tid 0..127 ----
    float m = g2;
    #pragma unroll
    for (int msk = 1; msk < 64; msk <<= 1) m = fmaxf(m, __shfl_xor(m, msk));
    if ((tid & 63) == 0) s_red[wave] = m;   // waves 2..7 write unused slots
    __syncthreads();
    const float gmax = fmaxf(s_red[0], s_red[1]);
    float e = (tid < D_) ? __expf(g2 - gmax) : 0.0f;
    float se = e;
    #pragma unroll
    for (int msk = 1; msk < 64; msk <<= 1) se += __shfl_xor(se, msk);
    if ((tid & 63) == 0) s_red[8 + wave] = se;
    __syncthreads();
    const float lse = __logf(s_red[8] + s_red[9]) + gmax;
    if (tid < D_) s_ls[tid] = g2 - lse;
    __syncthreads();

    // ---- Step 6: store out0 (broadcast ls) for this block's 16 nodes ----
    {
        const size_t off = (size_t)gnode * D_ + d0;
        *(float4*)(out + off) =
            make_float4(s_ls[d0], s_ls[d0 + 1], s_ls[d0 + 2], s_ls[d0 + 3]);
    }
}

extern "C" void kernel_launch(void* const* d_in, const int* in_sizes, int n_in,
                              void* d_out, int out_size, void* d_ws, size_t ws_size,
                              hipStream_t stream) {
    const float* x  = (const float*)d_in[0];
    const float* W0 = (const float*)d_in[1];
    const float* b0 = (const float*)d_in[2];
    const float* W1 = (const float*)d_in[3];
    const float* b1 = (const float*)d_in[4];
    const float* W2 = (const float*)d_in[5];
    const float* b2 = (const float*)d_in[6];
    // d_in[7] = edge_index (int32) — eliminated analytically.
    float* out = (float*)d_out;

    dim3 grid(256), block(512);
    hipLaunchKernelGGL(gcn_fused_kernel, grid, block, 0, stream,
                       x, W0, b0, W1, b1, W2, b2, out);
}